// Round 12
// baseline (105.206 us; speedup 1.0000x reference)
//
#include <hip/hip_runtime.h>

// N=1536 T=20 H=64 E=16 M=128
// Qf[j,k] (MFMA-frag-tile layout), P[j,k]: fp16 in d_ws; W2f: pre-fragmented
// W2 (16KB fp16). out[i] = max_j relu( relu(Q[j]-P[i]) @ W2 + b2 )
//
// R14 resubmit (previous round died to container infra, no data; R6
// precedent: unchanged resubmit succeeded). One safety tweak: gload16
// output constraint "=&v" (early-clobber) so the dest can never alias the
// address pair of a neighboring in-flight load.
//
// Theory: counted vmcnt. Ledger (R9-R13): matrix 45%, VALU 14%, ~40% idle
// at ~5 waves/CU -- fits one exposed L2 round-trip (~300cy) per tile
// (~930cy MFMA cluster) => compiler drains vmcnt(0) before each tile's
// first use instead of the counted wait the ping-pong permits (known
// HIP-compiler weakness; T4's +38-73% is exactly counted-vs-drain0).
// Fix: inline-asm global_load_dwordx4 prefetch (invisible to compiler
// waitcnt insertion) + explicit s_waitcnt vmcnt(4) + sched_barrier(0)
// (rule #18) before each compute_tile. Single lever vs R13 -- everything
// else unchanged (NI=3, W2f pre-frag, parity stagger, byte addr, setprio).

#define NN 1536
#define HH 64
#define EE 16
#define MM 128
#define TT 20

#define NI 3
#define NIGRP (NN / NI)       // 512 i-groups
#define JSPLIT 4
#define NTILE (96 / JSPLIT)   // 24 j-tiles of 16 per wave
#define HTILE (NTILE / 2)     // 12 per half-run

typedef _Float16 half8 __attribute__((ext_vector_type(8)));
typedef float f32x4 __attribute__((ext_vector_type(4)));

__device__ __forceinline__ half8 gload16(const void* p) {
  half8 r;
  asm volatile("global_load_dwordx4 %0, %1, off" : "=&v"(r) : "v"(p));
  return r;
}
__device__ __forceinline__ void vmwait4() {
  asm volatile("s_waitcnt vmcnt(4)" ::: "memory");
  __builtin_amdgcn_sched_barrier(0);
}
__device__ __forceinline__ void vmwait0() {
  asm volatile("s_waitcnt vmcnt(0)" ::: "memory");
  __builtin_amdgcn_sched_barrier(0);
}

// grid NN, block 128. Computes Qf (frag-tile layout), P, W2f, zero-inits out.
// Qf entry: A[row=j&15][k=m] for tile jt=j>>4 lands where reading lane
// l finds halfs jj at ((jt*4+ks)*64+l)*8+jj with k = ks*32 + (l>>4)*8 + jj
//   ->  ks=m>>5, l=((m>>3)&3)*16+(j&15), jj=m&7.   (verified R6-R13)
__global__ __launch_bounds__(128) void precompute_kernel(
    const float* __restrict__ hidden, const float* __restrict__ gt,
    const float* __restrict__ We, const float* __restrict__ be,
    const float* __restrict__ W1, const float* __restrict__ b1,
    const float* __restrict__ W2,
    _Float16* __restrict__ Qf, _Float16* __restrict__ P,
    _Float16* __restrict__ W2f, float* __restrict__ out)
{
  const int j = blockIdx.x;
  const int m = threadIdx.x;
  const float* hrow = hidden + j * HH;
  float a0 = 0.f, a1 = 0.f;
  #pragma unroll 8
  for (int h = 0; h < HH; h += 2) {
    a0 = fmaf(hrow[h],     W1[h * MM + m],       a0);
    a1 = fmaf(hrow[h + 1], W1[(h + 1) * MM + m], a1);
  }
  const float a = a0 + a1;
  float ve0 = 0.f, ve1 = 0.f, cm = b1[m];
  #pragma unroll
  for (int e = 0; e < EE; ++e) {
    float w1e = W1[(HH + e) * MM + m];
    ve0 = fmaf(We[e], w1e, ve0);       // We[0][e]
    ve1 = fmaf(We[EE + e], w1e, ve1);  // We[1][e]
    cm  = fmaf(be[e], w1e, cm);
  }
  const float e0 = gt[j * (2 * TT) + 2 * (TT - 1)];
  const float e1 = gt[j * (2 * TT) + 2 * (TT - 1) + 1];
  const float p = fmaf(e0, ve0, e1 * ve1);
  P[j * MM + m] = (_Float16)p;

  const int jt = j >> 4;
  const int ks = m >> 5;
  const int ln = ((m >> 3) & 3) * 16 + (j & 15);
  const int jj = m & 7;
  Qf[(((jt * 4) + ks) * 64 + ln) * 8 + jj] = (_Float16)(a + p + cm);

  if (m < HH) out[j * HH + m] = 0.f;

  // blocks 0..7: pre-fragment W2 -> W2f (verified R8-R13).
  // unit u = ct*256 + ksx*64 + l holds halfs jj with
  // W2f[u*8+jj] = (fp16) W2[(ksx*32 + (l>>4)*8 + jj)*HH + ct*16 + (l&15)]
  if (j < 8) {
    const int u = j * 128 + m;          // 0..1023
    const int ct = u >> 8;
    const int ksx = (u >> 6) & 3;
    const int l = u & 63;
    half8 w;
    #pragma unroll
    for (int t = 0; t < 8; ++t)
      w[t] = (_Float16)W2[(ksx * 32 + (l >> 4) * 8 + t) * HH + ct * 16 + (l & 15)];
    *(half8*)(W2f + (size_t)u * 8) = w;
  }
}

// grid NIGRP*JSPLIT = 2048, block 64 (1 wave). Wave: i0..i0+2, 24 j-tiles
// in two half-runs of 12 (parity stagger); counted-vmcnt reg ping-pong.
__global__ __launch_bounds__(64, 2) void pairmlp_max_kernel(
    const _Float16* __restrict__ Qf, const _Float16* __restrict__ P,
    const _Float16* __restrict__ W2f, const float* __restrict__ b2,
    float* __restrict__ out)
{
  const int lane = threadIdx.x;
  const int quad = lane >> 4;
  const int lcol = lane & 15;
  const int ig = blockIdx.x % NIGRP;  // consecutive blocks: same js ->
  const int js = blockIdx.x / NIGRP;  // same Q tile stream (L1/L2 reuse)
  const int i0 = ig * NI;
  const int par = blockIdx.x & 1;     // stagger parity

  // B fragments from pre-fragmented W2f: 16 coalesced 16B loads
  half8 bfrag[4][4];
  {
    const half8* wf = (const half8*)W2f + lane;
    #pragma unroll
    for (int ct = 0; ct < 4; ++ct)
      #pragma unroll
      for (int ks = 0; ks < 4; ++ks)
        bfrag[ct][ks] = wf[(ct * 4 + ks) * 64];
  }

  // P fragments for NI i's
  half8 pv[NI][4];
  #pragma unroll
  for (int ii = 0; ii < NI; ++ii) {
    const _Float16* prow = P + (i0 + ii) * MM + quad * 8;
    #pragma unroll
    for (int ks = 0; ks < 4; ++ks)
      pv[ii][ks] = *(const half8*)(prow + ks * 32);
  }

  float b2v[4];
  #pragma unroll
  for (int ct = 0; ct < 4; ++ct) b2v[ct] = b2[ct * 16 + lcol];

  float rmax[NI][4];
  #pragma unroll
  for (int ii = 0; ii < NI; ++ii)
    #pragma unroll
    for (int ct = 0; ct < 4; ++ct) rmax[ii][ct] = -3.0e38f;

  // byte base: tile jt at jt*4096, ks at +1024*ks, lane at +16*lane
  const char* qbytes = (const char*)Qf + (size_t)(js * NTILE) * 4096 + lane * 16;

  const half8 hz = 0;

  // compute one 16-j tile held in q0..q3 against all NI i's
  auto compute_tile = [&](half8 q0, half8 q1, half8 q2, half8 q3) {
    half8 qt[4] = {q0, q1, q2, q3};
    f32x4 acc[NI][4];
    #pragma unroll
    for (int ks = 0; ks < 4; ++ks) {
      __builtin_amdgcn_s_setprio(1);
      #pragma unroll
      for (int ii = 0; ii < NI; ++ii) {
        half8 s = qt[ks] - pv[ii][ks];
        s = __builtin_elementwise_max(s, hz);
        #pragma unroll
        for (int ct = 0; ct < 4; ++ct) {
          if (ks == 0)
            acc[ii][ct] = __builtin_amdgcn_mfma_f32_16x16x32_f16(
                s, bfrag[ct][0], f32x4{0.f, 0.f, 0.f, 0.f}, 0, 0, 0);
          else
            acc[ii][ct] = __builtin_amdgcn_mfma_f32_16x16x32_f16(
                s, bfrag[ct][ks], acc[ii][ct], 0, 0, 0);
        }
      }
      __builtin_amdgcn_s_setprio(0);
    }
    // C/D: col=lcol+ct*16, row(j)=quad*4+reg. Raw max; +b2/relu deferred.
    #pragma unroll
    for (int ii = 0; ii < NI; ++ii)
      #pragma unroll
      for (int ct = 0; ct < 4; ++ct) {
        const float t3 = fmaxf(fmaxf(acc[ii][ct][0], acc[ii][ct][1]), acc[ii][ct][2]);
        rmax[ii][ct] = fmaxf(fmaxf(t3, acc[ii][ct][3]), rmax[ii][ct]);
      }
  };

  // two half-runs of HTILE tiles; order swapped by parity (anti-phase stagger)
  for (int h = 0; h < 2; ++h) {
    const char* runb = qbytes + (((h ^ par) != 0) ? HTILE * 4096 : 0);
    const char* qp = runb;

    // prime: issue tile-0 loads (4 outstanding)
    half8 qc0 = gload16(qp);
    half8 qc1 = gload16(qp + 1024);
    half8 qc2 = gload16(qp + 2048);
    half8 qc3 = gload16(qp + 3072);

    for (int t = 0; t < HTILE; t += 2) {
      // issue tile t+1 loads (up to 8 outstanding)
      half8 qn0 = gload16(qp + 4096);
      half8 qn1 = gload16(qp + 5120);
      half8 qn2 = gload16(qp + 6144);
      half8 qn3 = gload16(qp + 7168);
      vmwait4();                       // tile t arrived; t+1 in flight
      compute_tile(qc0, qc1, qc2, qc3);

      if (t + 2 < HTILE) {
        // issue tile t+2 loads into qc (up to 8 outstanding)
        qc0 = gload16(qp + 8192);
        qc1 = gload16(qp + 9216);
        qc2 = gload16(qp + 10240);
        qc3 = gload16(qp + 11264);
        vmwait4();                     // tile t+1 arrived; t+2 in flight
      } else {
        vmwait0();                     // last pair: drain
      }
      compute_tile(qn0, qn1, qn2, qn3);

      qp += 8192;
    }
  }

  // combine quad-groups (different j rows, same col), then atomic max.
  #pragma unroll
  for (int ii = 0; ii < NI; ++ii)
    #pragma unroll
    for (int ct = 0; ct < 4; ++ct) {
      float v = rmax[ii][ct];
      v = fmaxf(v, __shfl_xor(v, 16, 64));
      v = fmaxf(v, __shfl_xor(v, 32, 64));
      v = fmaxf(v + b2v[ct], 0.f);
      if (quad == 0)
        atomicMax((unsigned*)(out + (i0 + ii) * HH + ct * 16 + lcol), __float_as_uint(v));
    }
}

extern "C" void kernel_launch(void* const* d_in, const int* in_sizes, int n_in,
                              void* d_out, int out_size, void* d_ws, size_t ws_size,
                              hipStream_t stream) {
  const float* hidden = (const float*)d_in[0];
  const float* gt     = (const float*)d_in[1];
  const float* We     = (const float*)d_in[2];
  const float* be     = (const float*)d_in[3];
  const float* W1     = (const float*)d_in[4];
  const float* b1     = (const float*)d_in[5];
  const float* W2     = (const float*)d_in[6];
  const float* b2     = (const float*)d_in[7];
  float* out = (float*)d_out;

  _Float16* Qf  = (_Float16*)d_ws;     // NN*MM fp16 (384KB), frag-tile layout
  _Float16* Ph  = Qf + NN * MM;        // NN*MM fp16 (384KB)
  _Float16* W2f = Ph + NN * MM;        // 4*4*64*8 fp16 (16KB), frag layout

  precompute_kernel<<<NN, 128, 0, stream>>>(hidden, gt, We, be, W1, b1, W2, Qf, Ph, W2f, out);
  pairmlp_max_kernel<<<NIGRP * JSPLIT, 64, 0, stream>>>(Qf, Ph, W2f, b2, out);
}